// Round 15
// baseline (159.415 us; speedup 1.0000x reference)
//
#include <hip/hip_runtime.h>
#include <stdint.h>

// QuantizedLinear: out[M,N] = (x[M,K] @ Wq^T) * scale[N] + bias[N]
// M = B*S = 4096, K = IN = 4096, N = OUT = 4096.
// Round 15: R14's winning structure (256x128 tile, BK=32, 4 waves of 128x64,
// triple-buffer 72 KB -> 2 blocks/CU, counted vmcnt(6)) with ONE change:
// K-loop unrolled x3 so buffer bases are compile-time constants (kt%3 static
// per slot) -> LDS frag addresses become immediates, kills per-iter VALU
// address recomputation (VALUBusy 26% target ~18%). cvt passes merged into
// one launch. Everything else byte-identical to R14.

#define M_DIM 4096
#define N_DIM 4096
#define K_DIM 4096
#define BM 256
#define BN 128
#define BK 32
#define KT_N (K_DIM / BK)      // 128 K-tiles
#define A_TILE_SHORTS 8192     // 256x32 f16 = 16 KB
#define B_TILE_SHORTS 4096     // 128x32 f16 = 8 KB
#define BUF_SHORTS 12288       // A + B = 24 KB
#define B_OFF 8192

typedef _Float16 f16x8 __attribute__((ext_vector_type(8)));
typedef __bf16   bf16x8v __attribute__((ext_vector_type(8)));
typedef float    f32x4 __attribute__((ext_vector_type(4)));

__device__ __forceinline__ unsigned short f32_f16_bits(float f) {
    _Float16 h = (_Float16)f;
    return __builtin_bit_cast(unsigned short, h);
}

__device__ __forceinline__ void gld16(const unsigned short* g, unsigned short* l) {
    __builtin_amdgcn_global_load_lds(
        (const __attribute__((address_space(1))) unsigned int*)g,
        (__attribute__((address_space(3))) unsigned int*)l,
        16, 0, 0);
}

// ---------- fused pre-pass: x -> AT (blocks 0..2047), Wq -> BT (2048..4095) ----------
// AT: [mi(16)][kt(128)] tiles of [ks(4)][r(256)][8]
// BT: [ni(32)][kt(128)] tiles of [ks(4)][c(128)][8]
__global__ __launch_bounds__(256) void cvt_fused(const float* __restrict__ x,
                                                 const int* __restrict__ wq,
                                                 unsigned short* __restrict__ AT,
                                                 unsigned short* __restrict__ BT) {
    const int b = blockIdx.x;
    const int t = threadIdx.x;
    if (b < 2048) {
        const int mi = b >> 7;
        const int kt = b & 127;
        const int r  = t;             // 0..255
        const float* xp = x + (size_t)(mi * 256 + r) * K_DIM + kt * 32;
        unsigned short hh[32];
        #pragma unroll
        for (int j4 = 0; j4 < 8; ++j4) {
            float4 v = *(const float4*)(xp + j4 * 4);
            hh[j4*4+0] = f32_f16_bits(v.x);
            hh[j4*4+1] = f32_f16_bits(v.y);
            hh[j4*4+2] = f32_f16_bits(v.z);
            hh[j4*4+3] = f32_f16_bits(v.w);
        }
        unsigned short* o = AT + (size_t)(mi * KT_N + kt) * A_TILE_SHORTS + r * 8;
        #pragma unroll
        for (int ks = 0; ks < 4; ++ks) {
            uint4 p;
            p.x = (unsigned)hh[ks*8+0] | ((unsigned)hh[ks*8+1] << 16);
            p.y = (unsigned)hh[ks*8+2] | ((unsigned)hh[ks*8+3] << 16);
            p.z = (unsigned)hh[ks*8+4] | ((unsigned)hh[ks*8+5] << 16);
            p.w = (unsigned)hh[ks*8+6] | ((unsigned)hh[ks*8+7] << 16);
            *(uint4*)(o + ks * 2048) = p;     // (ks*256 + r)*8
        }
    } else {
        const int bb2 = b - 2048;
        const int ni  = bb2 >> 6;
        const int kt2 = bb2 & 63;
        const int c   = t & 127;
        const int kt  = kt2 * 2 + (t >> 7);
        const int* wp = wq + (size_t)(ni * 128 + c) * K_DIM + kt * 32;
        unsigned short bb[32];
        #pragma unroll
        for (int j4 = 0; j4 < 8; ++j4) {
            int4 v = *(const int4*)(wp + j4 * 4);
            bb[j4*4+0] = f32_f16_bits((float)v.x);
            bb[j4*4+1] = f32_f16_bits((float)v.y);
            bb[j4*4+2] = f32_f16_bits((float)v.z);
            bb[j4*4+3] = f32_f16_bits((float)v.w);
        }
        unsigned short* ob = BT + (size_t)(ni * KT_N + kt) * B_TILE_SHORTS + c * 8;
        #pragma unroll
        for (int ks = 0; ks < 4; ++ks) {
            uint4 p;
            p.x = (unsigned)bb[ks*8+0] | ((unsigned)bb[ks*8+1] << 16);
            p.y = (unsigned)bb[ks*8+2] | ((unsigned)bb[ks*8+3] << 16);
            p.z = (unsigned)bb[ks*8+4] | ((unsigned)bb[ks*8+5] << 16);
            p.w = (unsigned)bb[ks*8+6] | ((unsigned)bb[ks*8+7] << 16);
            *(uint4*)(ob + ks * 1024) = p;    // (ks*128 + c)*8
        }
    }
}

// ---------- GEMM: 256x128 tile, 4 waves (128x64 each), triple-buffer, x3 unroll ----------
__global__ __launch_bounds__(256, 2) void gemm_pipe(
    const unsigned short* __restrict__ AT,
    const unsigned short* __restrict__ BT,
    const float* __restrict__ scale, const float* __restrict__ bias,
    float* __restrict__ out)
{
    __shared__ unsigned short lds[3 * BUF_SHORTS];   // 72 KB -> 2 blocks/CU

    const int t    = threadIdx.x;     // 0..255
    const int lane = t & 63;
    const int wid  = t >> 6;          // 0..3
    const int wr   = wid >> 1;        // 0..1  (128-row slab)
    const int wc   = wid & 1;         // 0..1  (64-col slab)
    const int lr   = lane & 15;
    const int ksf  = lane >> 4;

    // XCD swizzle: 512 blocks, 512 % 8 == 0 -> bijective
    const int bid = blockIdx.x;
    const int swz = (bid & 7) * 64 + (bid >> 3);
    const int mi  = swz & 15;         // 0..15
    const int ni  = swz >> 4;         // 0..31

    const int lbA = (t & ~63) * 8;    // wave-uniform LDS base (shorts)
    const unsigned short* gA = AT + (size_t)mi * KT_N * A_TILE_SHORTS + t * 8;
    const unsigned short* gB = BT + (size_t)ni * KT_N * B_TILE_SHORTS + t * 8;

#define STAGE(bufbase, kt) do {                                               \
    _Pragma("unroll")                                                         \
    for (int j = 0; j < 4; ++j)                                               \
        gld16(gA + (size_t)(kt) * A_TILE_SHORTS + j * 2048,                   \
              lds + (bufbase) + lbA + j * 2048);                              \
    _Pragma("unroll")                                                         \
    for (int j = 0; j < 2; ++j)                                               \
        gld16(gB + (size_t)(kt) * B_TILE_SHORTS + j * 2048,                   \
              lds + (bufbase) + B_OFF + lbA + j * 2048);                      \
} while (0)

    int offA[8], offB[4];
    #pragma unroll
    for (int m = 0; m < 8; ++m)
        offA[m] = (ksf * 256 + wr * 128 + m * 16 + lr) * 8;        // A: [ks4][256][8]
    #pragma unroll
    for (int n = 0; n < 4; ++n)
        offB[n] = B_OFF + (ksf * 128 + wc * 64 + n * 16 + lr) * 8; // B: [ks4][128][8]

    f32x4 acc[8][4];
    #pragma unroll
    for (int m = 0; m < 8; ++m)
        #pragma unroll
        for (int n = 0; n < 4; ++n)
            acc[m][n] = (f32x4){0.f, 0.f, 0.f, 0.f};

    // one K-step; CURB/STGB are COMPILE-TIME buffer bases (kt%3 static per slot)
#define KSTEP(kt, CURB, STGB, DO_STAGE, VMC) do {                             \
    const unsigned short* Lb = lds + (CURB);                                  \
    f16x8 a4[8], b4[4];                                                       \
    _Pragma("unroll")                                                         \
    for (int n = 0; n < 4; ++n) b4[n] = *(const f16x8*)(Lb + offB[n]);        \
    _Pragma("unroll")                                                         \
    for (int m = 0; m < 8; ++m) a4[m] = *(const f16x8*)(Lb + offA[m]);        \
    if (DO_STAGE) STAGE((STGB), (kt) + 2);                                    \
    asm volatile("s_waitcnt lgkmcnt(0)" ::: "memory");                        \
    __builtin_amdgcn_sched_barrier(0);                                        \
    __builtin_amdgcn_s_setprio(1);                                            \
    _Pragma("unroll")                                                         \
    for (int m = 0; m < 8; ++m)                                               \
        _Pragma("unroll")                                                     \
        for (int n = 0; n < 4; ++n)                                           \
            acc[m][n] = __builtin_amdgcn_mfma_f32_16x16x32_f16(               \
                a4[m], b4[n], acc[m][n], 0, 0, 0);                            \
    __builtin_amdgcn_s_setprio(0);                                            \
    asm volatile("s_waitcnt vmcnt(" #VMC ")" ::: "memory");                   \
    __builtin_amdgcn_s_barrier();                                             \
} while (0)

    // prologue: tiles 0,1 -> buffers 0,1; vmcnt(6): tile 0 landed, tile 1 in flight
    STAGE(0, 0);
    STAGE(BUF_SHORTS, 1);
    asm volatile("s_waitcnt vmcnt(6)" ::: "memory");
    __builtin_amdgcn_s_barrier();

    // main: kt = 0..125 (42 x 3 steps), buffer = kt%3, stage target = (kt+2)%3
    for (int k3 = 0; k3 < 126; k3 += 3) {
        KSTEP(k3 + 0, 0 * BUF_SHORTS, 2 * BUF_SHORTS, true, 6);
        KSTEP(k3 + 1, 1 * BUF_SHORTS, 0 * BUF_SHORTS, true, 6);
        KSTEP(k3 + 2, 2 * BUF_SHORTS, 1 * BUF_SHORTS, true, 6);
    }
    // tail: kt = 126 (buf 0), kt = 127 (buf 1); no staging, drain to 0
    KSTEP(126, 0 * BUF_SHORTS, 0, false, 0);
    KSTEP(127, 1 * BUF_SHORTS, 0, false, 0);
#undef KSTEP
#undef STAGE

    // epilogue: C/D layout col=lane&15, row=(lane>>4)*4+j (m89-verified)
    #pragma unroll
    for (int n = 0; n < 4; ++n) {
        const int col = ni * BN + wc * 64 + n * 16 + lr;
        const float sc = scale[col];
        const float bi = bias[col];
        #pragma unroll
        for (int m = 0; m < 8; ++m) {
            const int r0 = mi * BM + wr * 128 + m * 16 + ksf * 4;
            #pragma unroll
            for (int j = 0; j < 4; ++j)
                out[(size_t)(r0 + j) * N_DIM + col] = acc[m][n][j] * sc + bi;
        }
    }
}

// ---------- fallback (ws too small): reg-staged 2-plane bf16, proven structure ----------
__device__ __forceinline__ unsigned short f32_bf16_rne(float f) {
    unsigned u = __float_as_uint(f);
    u += 0x7FFFu + ((u >> 16) & 1u);
    return (unsigned short)(u >> 16);
}

__device__ __forceinline__ void cvt2(float a, float b, unsigned& hi2, unsigned& lo2) {
    unsigned short ha = f32_bf16_rne(a), hb = f32_bf16_rne(b);
    float fa = __uint_as_float((unsigned)ha << 16);
    float fb = __uint_as_float((unsigned)hb << 16);
    unsigned short la = f32_bf16_rne(a - fa), lb = f32_bf16_rne(b - fb);
    hi2 = (unsigned)ha | ((unsigned)hb << 16);
    lo2 = (unsigned)la | ((unsigned)lb << 16);
}

__global__ __launch_bounds__(256) void gemm_fb(
    const float* __restrict__ X, const int* __restrict__ Wq,
    const float* __restrict__ scale, const float* __restrict__ bias,
    float* __restrict__ out)
{
    __shared__ unsigned short sAh[4 * 128 * 8];
    __shared__ unsigned short sAl[4 * 128 * 8];
    __shared__ unsigned short sB [4 * 128 * 8];

    const int t    = threadIdx.x;
    const int lane = t & 63;
    const int wid  = t >> 6;
    const int brow = blockIdx.y * 128;
    const int bcol = blockIdx.x * 128;

    const int c1 = t,        c2 = t + 256;
    const int r1 = c1 & 127, s1 = c1 >> 7;
    const int r2 = c2 & 127, s2 = c2 >> 7;

    const int wr  = wid >> 1, wc = wid & 1;
    const int lr  = lane & 15;
    const int ksf = lane >> 4;

    f32x4 acc[4][4];
    #pragma unroll
    for (int m = 0; m < 4; ++m)
        #pragma unroll
        for (int n = 0; n < 4; ++n)
            acc[m][n] = (f32x4){0.f, 0.f, 0.f, 0.f};

    for (int k0 = 0; k0 < K_DIM; k0 += 32) {
        #pragma unroll
        for (int cc = 0; cc < 2; ++cc) {
            const int c = cc ? c2 : c1;
            const int r = cc ? r2 : r1;
            const int s = cc ? s2 : s1;
            const float* xa = X + (size_t)(brow + r) * K_DIM + k0 + s * 8;
            float4 v0 = *(const float4*)(xa);
            float4 v1 = *(const float4*)(xa + 4);
            uint4 hv, lv;
            cvt2(v0.x, v0.y, hv.x, lv.x);
            cvt2(v0.z, v0.w, hv.y, lv.y);
            cvt2(v1.x, v1.y, hv.z, lv.z);
            cvt2(v1.z, v1.w, hv.w, lv.w);
            *(uint4*)(sAh + c * 8) = hv;
            *(uint4*)(sAl + c * 8) = lv;

            const int* wa = Wq + (size_t)(bcol + r) * K_DIM + k0 + s * 8;
            int4 w0 = *(const int4*)(wa);
            int4 w1 = *(const int4*)(wa + 4);
            uint4 wv;
            wv.x = (unsigned)f32_bf16_rne((float)w0.x) | ((unsigned)f32_bf16_rne((float)w0.y) << 16);
            wv.y = (unsigned)f32_bf16_rne((float)w0.z) | ((unsigned)f32_bf16_rne((float)w0.w) << 16);
            wv.z = (unsigned)f32_bf16_rne((float)w1.x) | ((unsigned)f32_bf16_rne((float)w1.y) << 16);
            wv.w = (unsigned)f32_bf16_rne((float)w1.z) | ((unsigned)f32_bf16_rne((float)w1.w) << 16);
            *(uint4*)(sB + c * 8) = wv;
        }
        __syncthreads();

        bf16x8v ah[4], al[4], bb[4];
        #pragma unroll
        for (int m = 0; m < 4; ++m) {
            const int row = wr * 64 + m * 16 + lr;
            ah[m] = *(const bf16x8v*)(sAh + (ksf * 128 + row) * 8);
            al[m] = *(const bf16x8v*)(sAl + (ksf * 128 + row) * 8);
        }
        #pragma unroll
        for (int n = 0; n < 4; ++n) {
            const int row = wc * 64 + n * 16 + lr;
            bb[n] = *(const bf16x8v*)(sB + (ksf * 128 + row) * 8);
        }

        #pragma unroll
        for (int m = 0; m < 4; ++m)
            #pragma unroll
            for (int n = 0; n < 4; ++n) {
                acc[m][n] = __builtin_amdgcn_mfma_f32_16x16x32_bf16(ah[m], bb[n], acc[m][n], 0, 0, 0);
                acc[m][n] = __builtin_amdgcn_mfma_f32_16x16x32_bf16(al[m], bb[n], acc[m][n], 0, 0, 0);
            }
        __syncthreads();
    }

    #pragma unroll
    for (int n = 0; n < 4; ++n) {
        const int col = bcol + wc * 64 + n * 16 + lr;
        const float sc = scale[col];
        const float bi = bias[col];
        #pragma unroll
        for (int m = 0; m < 4; ++m) {
            const int r0 = brow + wr * 64 + m * 16 + ksf * 4;
            #pragma unroll
            for (int j = 0; j < 4; ++j)
                out[(size_t)(r0 + j) * N_DIM + col] = acc[m][n][j] * sc + bi;
        }
    }
}

extern "C" void kernel_launch(void* const* d_in, const int* in_sizes, int n_in,
                              void* d_out, int out_size, void* d_ws, size_t ws_size,
                              hipStream_t stream) {
    const float* x     = (const float*)d_in[0];
    const int*   wq    = (const int*)d_in[1];
    const float* scale = (const float*)d_in[2];
    const float* bias  = (const float*)d_in[3];
    float*       out   = (float*)d_out;

    const size_t planeElems = (size_t)M_DIM * K_DIM;        // 16,777,216
    const size_t planeBytes = planeElems * sizeof(unsigned short);  // 32 MiB

    if (ws_size >= 2 * planeBytes) {
        unsigned short* AT = (unsigned short*)d_ws;
        unsigned short* BT = AT + planeElems;
        cvt_fused<<<4096, 256, 0, stream>>>(x, wq, AT, BT);
        gemm_pipe<<<(M_DIM / BM) * (N_DIM / BN), 256, 0, stream>>>(AT, BT, scale, bias, out);
    } else {
        dim3 grid(N_DIM / 128, M_DIM / 128);
        gemm_fb<<<grid, 256, 0, stream>>>(x, wq, scale, bias, out);
    }
}

// Round 16
// 153.731 us; speedup vs baseline: 1.0370x; 1.0370x over previous
//
#include <hip/hip_runtime.h>
#include <stdint.h>

// QuantizedLinear: out[M,N] = (x[M,K] @ Wq^T) * scale[N] + bias[N]
// M = B*S = 4096, K = IN = 4096, N = OUT = 4096.
// Round 16: REVERT to R14 verbatim (measured best: gemm 116.5us, total 154.4us).
// R15's x3 unroll overflowed the I-cache (FETCH_SIZE 147->274MB = code refetch)
// and regressed; rolled loop body restored. Structure: 256x128 tile, BK=32,
// 4 waves (each 128x64: 12 ds_read : 32 MFMA), triple-buffer 72 KB ->
// 2 blocks/CU (cross-block desync hides the LDS window), counted vmcnt(6).

#define M_DIM 4096
#define N_DIM 4096
#define K_DIM 4096
#define BM 256
#define BN 128
#define BK 32
#define KT_N (K_DIM / BK)      // 128 K-tiles
#define A_TILE_SHORTS 8192     // 256x32 f16 = 16 KB
#define B_TILE_SHORTS 4096     // 128x32 f16 = 8 KB
#define BUF_SHORTS 12288       // A + B = 24 KB
#define B_OFF 8192

typedef _Float16 f16x8 __attribute__((ext_vector_type(8)));
typedef __bf16   bf16x8v __attribute__((ext_vector_type(8)));
typedef float    f32x4 __attribute__((ext_vector_type(4)));

__device__ __forceinline__ unsigned short f32_f16_bits(float f) {
    _Float16 h = (_Float16)f;
    return __builtin_bit_cast(unsigned short, h);
}

__device__ __forceinline__ void gld16(const unsigned short* g, unsigned short* l) {
    __builtin_amdgcn_global_load_lds(
        (const __attribute__((address_space(1))) unsigned int*)g,
        (__attribute__((address_space(3))) unsigned int*)l,
        16, 0, 0);
}

// ---------- pre-pass: x (f32) -> f16 plane, TILED layout ----------
// AT: [mi(16)][kt(128)] tiles of [ks(4)][r(256)][8]  (exact 256xBK LDS image)
__global__ __launch_bounds__(256) void cvt_x_f16(const float* __restrict__ x,
                                                 unsigned short* __restrict__ AT) {
    const int b  = blockIdx.x;        // 16 * 128 = 2048
    const int mi = b >> 7;
    const int kt = b & 127;
    const int r  = threadIdx.x;       // 0..255

    const float* xp = x + (size_t)(mi * 256 + r) * K_DIM + kt * 32;
    unsigned short hh[32];
    #pragma unroll
    for (int j4 = 0; j4 < 8; ++j4) {
        float4 v = *(const float4*)(xp + j4 * 4);
        hh[j4*4+0] = f32_f16_bits(v.x);
        hh[j4*4+1] = f32_f16_bits(v.y);
        hh[j4*4+2] = f32_f16_bits(v.z);
        hh[j4*4+3] = f32_f16_bits(v.w);
    }
    unsigned short* o = AT + (size_t)(mi * KT_N + kt) * A_TILE_SHORTS + r * 8;
    #pragma unroll
    for (int ks = 0; ks < 4; ++ks) {
        uint4 p;
        p.x = (unsigned)hh[ks*8+0] | ((unsigned)hh[ks*8+1] << 16);
        p.y = (unsigned)hh[ks*8+2] | ((unsigned)hh[ks*8+3] << 16);
        p.z = (unsigned)hh[ks*8+4] | ((unsigned)hh[ks*8+5] << 16);
        p.w = (unsigned)hh[ks*8+6] | ((unsigned)hh[ks*8+7] << 16);
        *(uint4*)(o + ks * 2048) = p;     // (ks*256 + r)*8
    }
}

// ---------- pre-pass: Wq (int) -> f16 plane (exact), BN=128 TILED layout ----------
// BT: [ni(32)][kt(128)] tiles of [ks(4)][c(128)][8]  (8 KB tiles)
__global__ __launch_bounds__(256) void cvt_w_f16(const int* __restrict__ wq,
                                                 unsigned short* __restrict__ BT) {
    const int b   = blockIdx.x;       // 32 * 64 = 2048
    const int ni  = b >> 6;
    const int kt2 = b & 63;
    const int t   = threadIdx.x;
    const int c   = t & 127;
    const int kt  = kt2 * 2 + (t >> 7);

    const int* wp = wq + (size_t)(ni * 128 + c) * K_DIM + kt * 32;
    unsigned short bb[32];
    #pragma unroll
    for (int j4 = 0; j4 < 8; ++j4) {
        int4 v = *(const int4*)(wp + j4 * 4);
        bb[j4*4+0] = f32_f16_bits((float)v.x);
        bb[j4*4+1] = f32_f16_bits((float)v.y);
        bb[j4*4+2] = f32_f16_bits((float)v.z);
        bb[j4*4+3] = f32_f16_bits((float)v.w);
    }
    unsigned short* ob = BT + (size_t)(ni * KT_N + kt) * B_TILE_SHORTS + c * 8;
    #pragma unroll
    for (int ks = 0; ks < 4; ++ks) {
        uint4 p;
        p.x = (unsigned)bb[ks*8+0] | ((unsigned)bb[ks*8+1] << 16);
        p.y = (unsigned)bb[ks*8+2] | ((unsigned)bb[ks*8+3] << 16);
        p.z = (unsigned)bb[ks*8+4] | ((unsigned)bb[ks*8+5] << 16);
        p.w = (unsigned)bb[ks*8+6] | ((unsigned)bb[ks*8+7] << 16);
        *(uint4*)(ob + ks * 1024) = p;    // (ks*128 + c)*8
    }
}

// ---------- GEMM: 256x128 tile, 4 waves (128x64 each), triple-buffer, R6 loop ----------
__global__ __launch_bounds__(256, 2) void gemm_pipe(
    const unsigned short* __restrict__ AT,
    const unsigned short* __restrict__ BT,
    const float* __restrict__ scale, const float* __restrict__ bias,
    float* __restrict__ out)
{
    __shared__ unsigned short lds[3 * BUF_SHORTS];   // 72 KB -> 2 blocks/CU

    const int t    = threadIdx.x;     // 0..255
    const int lane = t & 63;
    const int wid  = t >> 6;          // 0..3
    const int wr   = wid >> 1;        // 0..1  (128-row slab)
    const int wc   = wid & 1;         // 0..1  (64-col slab)
    const int lr   = lane & 15;
    const int ksf  = lane >> 4;

    // XCD swizzle: 512 blocks, 512 % 8 == 0 -> bijective; mi varies fastest
    // within an XCD -> B panels L2-resident with 16x reuse.
    const int bid = blockIdx.x;
    const int swz = (bid & 7) * 64 + (bid >> 3);
    const int mi  = swz & 15;         // 0..15
    const int ni  = swz >> 4;         // 0..31

    // staging: A tile = 1024 chunks (thread t owns t+256j, j=0..3),
    //          B tile = 512 chunks (j=0..1). LDS dest = wave-uniform + lane*16.
    const int lbA = (t & ~63) * 8;    // shorts
    const unsigned short* gA = AT + (size_t)mi * KT_N * A_TILE_SHORTS + t * 8;
    const unsigned short* gB = BT + (size_t)ni * KT_N * B_TILE_SHORTS + t * 8;

#define STAGE(bufbase, kt) do {                                               \
    _Pragma("unroll")                                                         \
    for (int j = 0; j < 4; ++j)                                               \
        gld16(gA + (size_t)(kt) * A_TILE_SHORTS + j * 2048,                   \
              lds + (bufbase) + lbA + j * 2048);                              \
    _Pragma("unroll")                                                         \
    for (int j = 0; j < 2; ++j)                                               \
        gld16(gB + (size_t)(kt) * B_TILE_SHORTS + j * 2048,                   \
              lds + (bufbase) + B_OFF + lbA + j * 2048);                      \
} while (0)

    int offA[8], offB[4];
    #pragma unroll
    for (int m = 0; m < 8; ++m)
        offA[m] = (ksf * 256 + wr * 128 + m * 16 + lr) * 8;      // A: [ks4][256][8]
    #pragma unroll
    for (int n = 0; n < 4; ++n)
        offB[n] = B_OFF + (ksf * 128 + wc * 64 + n * 16 + lr) * 8; // B: [ks4][128][8]

    f32x4 acc[8][4];
    #pragma unroll
    for (int m = 0; m < 8; ++m)
        #pragma unroll
        for (int n = 0; n < 4; ++n)
            acc[m][n] = (f32x4){0.f, 0.f, 0.f, 0.f};

    // prologue: tiles 0,1 -> buffers 0,1; vmcnt(6): tile 0 landed, tile 1 in flight
    STAGE(0, 0);
    STAGE(BUF_SHORTS, 1);
    asm volatile("s_waitcnt vmcnt(6)" ::: "memory");
    __builtin_amdgcn_s_barrier();

    int curB = 0;
    int preB = 2 * BUF_SHORTS;

    for (int kt = 0; kt < KT_N; ++kt) {
        const unsigned short* Lb = lds + curB;

        f16x8 a4[8], b4[4];
        #pragma unroll
        for (int n = 0; n < 4; ++n) b4[n] = *(const f16x8*)(Lb + offB[n]);
        #pragma unroll
        for (int m = 0; m < 8; ++m) a4[m] = *(const f16x8*)(Lb + offA[m]);

        if (kt + 2 < KT_N) STAGE(preB, kt + 2);   // 2-deep prefetch

        asm volatile("s_waitcnt lgkmcnt(0)" ::: "memory");
        __builtin_amdgcn_sched_barrier(0);
        __builtin_amdgcn_s_setprio(1);
        #pragma unroll
        for (int m = 0; m < 8; ++m)
            #pragma unroll
            for (int n = 0; n < 4; ++n)
                acc[m][n] = __builtin_amdgcn_mfma_f32_16x16x32_f16(a4[m], b4[n], acc[m][n], 0, 0, 0);
        __builtin_amdgcn_s_setprio(0);

        // counted: tile kt+1's 6 loads landed; kt+2's 6 stay in flight
        if (kt + 2 < KT_N) asm volatile("s_waitcnt vmcnt(6)" ::: "memory");
        else               asm volatile("s_waitcnt vmcnt(0)" ::: "memory");
        __builtin_amdgcn_s_barrier();

        curB = (curB == 2 * BUF_SHORTS) ? 0 : curB + BUF_SHORTS;
        preB = (preB == 2 * BUF_SHORTS) ? 0 : preB + BUF_SHORTS;
    }
#undef STAGE

    // epilogue: C/D layout col=lane&15, row=(lane>>4)*4+j (m89-verified)
    #pragma unroll
    for (int n = 0; n < 4; ++n) {
        const int col = ni * BN + wc * 64 + n * 16 + lr;
        const float sc = scale[col];
        const float bi = bias[col];
        #pragma unroll
        for (int m = 0; m < 8; ++m) {
            const int r0 = mi * BM + wr * 128 + m * 16 + ksf * 4;
            #pragma unroll
            for (int j = 0; j < 4; ++j)
                out[(size_t)(r0 + j) * N_DIM + col] = acc[m][n][j] * sc + bi;
        }
    }
}

// ---------- fallback (ws too small): reg-staged 2-plane bf16, proven structure ----------
__device__ __forceinline__ unsigned short f32_bf16_rne(float f) {
    unsigned u = __float_as_uint(f);
    u += 0x7FFFu + ((u >> 16) & 1u);
    return (unsigned short)(u >> 16);
}

__device__ __forceinline__ void cvt2(float a, float b, unsigned& hi2, unsigned& lo2) {
    unsigned short ha = f32_bf16_rne(a), hb = f32_bf16_rne(b);
    float fa = __uint_as_float((unsigned)ha << 16);
    float fb = __uint_as_float((unsigned)hb << 16);
    unsigned short la = f32_bf16_rne(a - fa), lb = f32_bf16_rne(b - fb);
    hi2 = (unsigned)ha | ((unsigned)hb << 16);
    lo2 = (unsigned)la | ((unsigned)lb << 16);
}

__global__ __launch_bounds__(256) void gemm_fb(
    const float* __restrict__ X, const int* __restrict__ Wq,
    const float* __restrict__ scale, const float* __restrict__ bias,
    float* __restrict__ out)
{
    __shared__ unsigned short sAh[4 * 128 * 8];
    __shared__ unsigned short sAl[4 * 128 * 8];
    __shared__ unsigned short sB [4 * 128 * 8];

    const int t    = threadIdx.x;
    const int lane = t & 63;
    const int wid  = t >> 6;
    const int brow = blockIdx.y * 128;
    const int bcol = blockIdx.x * 128;

    const int c1 = t,        c2 = t + 256;
    const int r1 = c1 & 127, s1 = c1 >> 7;
    const int r2 = c2 & 127, s2 = c2 >> 7;

    const int wr  = wid >> 1, wc = wid & 1;
    const int lr  = lane & 15;
    const int ksf = lane >> 4;

    f32x4 acc[4][4];
    #pragma unroll
    for (int m = 0; m < 4; ++m)
        #pragma unroll
        for (int n = 0; n < 4; ++n)
            acc[m][n] = (f32x4){0.f, 0.f, 0.f, 0.f};

    for (int k0 = 0; k0 < K_DIM; k0 += 32) {
        #pragma unroll
        for (int cc = 0; cc < 2; ++cc) {
            const int c = cc ? c2 : c1;
            const int r = cc ? r2 : r1;
            const int s = cc ? s2 : s1;
            const float* xa = X + (size_t)(brow + r) * K_DIM + k0 + s * 8;
            float4 v0 = *(const float4*)(xa);
            float4 v1 = *(const float4*)(xa + 4);
            uint4 hv, lv;
            cvt2(v0.x, v0.y, hv.x, lv.x);
            cvt2(v0.z, v0.w, hv.y, lv.y);
            cvt2(v1.x, v1.y, hv.z, lv.z);
            cvt2(v1.z, v1.w, hv.w, lv.w);
            *(uint4*)(sAh + c * 8) = hv;
            *(uint4*)(sAl + c * 8) = lv;

            const int* wa = Wq + (size_t)(bcol + r) * K_DIM + k0 + s * 8;
            int4 w0 = *(const int4*)(wa);
            int4 w1 = *(const int4*)(wa + 4);
            uint4 wv;
            wv.x = (unsigned)f32_bf16_rne((float)w0.x) | ((unsigned)f32_bf16_rne((float)w0.y) << 16);
            wv.y = (unsigned)f32_bf16_rne((float)w0.z) | ((unsigned)f32_bf16_rne((float)w0.w) << 16);
            wv.z = (unsigned)f32_bf16_rne((float)w1.x) | ((unsigned)f32_bf16_rne((float)w1.y) << 16);
            wv.w = (unsigned)f32_bf16_rne((float)w1.z) | ((unsigned)f32_bf16_rne((float)w1.w) << 16);
            *(uint4*)(sB + c * 8) = wv;
        }
        __syncthreads();

        bf16x8v ah[4], al[4], bb[4];
        #pragma unroll
        for (int m = 0; m < 4; ++m) {
            const int row = wr * 64 + m * 16 + lr;
            ah[m] = *(const bf16x8v*)(sAh + (ksf * 128 + row) * 8);
            al[m] = *(const bf16x8v*)(sAl + (ksf * 128 + row) * 8);
        }
        #pragma unroll
        for (int n = 0; n < 4; ++n) {
            const int row = wc * 64 + n * 16 + lr;
            bb[n] = *(const bf16x8v*)(sB + (ksf * 128 + row) * 8);
        }

        #pragma unroll
        for (int m = 0; m < 4; ++m)
            #pragma unroll
            for (int n = 0; n < 4; ++n) {
                acc[m][n] = __builtin_amdgcn_mfma_f32_16x16x32_bf16(ah[m], bb[n], acc[m][n], 0, 0, 0);
                acc[m][n] = __builtin_amdgcn_mfma_f32_16x16x32_bf16(al[m], bb[n], acc[m][n], 0, 0, 0);
            }
        __syncthreads();
    }

    #pragma unroll
    for (int n = 0; n < 4; ++n) {
        const int col = bcol + wc * 64 + n * 16 + lr;
        const float sc = scale[col];
        const float bi = bias[col];
        #pragma unroll
        for (int m = 0; m < 4; ++m) {
            const int r0 = brow + wr * 64 + m * 16 + ksf * 4;
            #pragma unroll
            for (int j = 0; j < 4; ++j)
                out[(size_t)(r0 + j) * N_DIM + col] = acc[m][n][j] * sc + bi;
        }
    }
}

extern "C" void kernel_launch(void* const* d_in, const int* in_sizes, int n_in,
                              void* d_out, int out_size, void* d_ws, size_t ws_size,
                              hipStream_t stream) {
    const float* x     = (const float*)d_in[0];
    const int*   wq    = (const int*)d_in[1];
    const float* scale = (const float*)d_in[2];
    const float* bias  = (const float*)d_in[3];
    float*       out   = (float*)d_out;

    const size_t planeElems = (size_t)M_DIM * K_DIM;        // 16,777,216
    const size_t planeBytes = planeElems * sizeof(unsigned short);  // 32 MiB

    if (ws_size >= 2 * planeBytes) {
        unsigned short* AT = (unsigned short*)d_ws;
        unsigned short* BT = AT + planeElems;
        cvt_x_f16<<<2048, 256, 0, stream>>>(x, AT);
        cvt_w_f16<<<2048, 256, 0, stream>>>(wq, BT);
        gemm_pipe<<<(M_DIM / BM) * (N_DIM / BN), 256, 0, stream>>>(AT, BT, scale, bias, out);
    } else {
        dim3 grid(N_DIM / 128, M_DIM / 128);
        gemm_fb<<<grid, 256, 0, stream>>>(x, wq, scale, bias, out);
    }
}